// Round 15
// baseline (115.702 us; speedup 1.0000x reference)
//
#include <hip/hip_runtime.h>
#include <cstdint>

typedef float f32x4 __attribute__((ext_vector_type(4)));
typedef long longx2 __attribute__((ext_vector_type(2)));
typedef unsigned char u8;
typedef unsigned short u16;
typedef unsigned int u32;
typedef unsigned long long u64;

#define B_N 8
#define T_N 2048
#define D_N 512
#define TAU 5.0f
#define NROW (B_N * T_N)    // 16384
// exp(TAU*s - 1) == exp2(K1*s - K2)
#define K1E 7.213475204444817f
#define K2E 1.4426950408889634f

#define WAITV(n) asm volatile("s_waitcnt vmcnt(" #n ")" ::: "memory")
#define WAITL0   asm volatile("s_waitcnt lgkmcnt(0)" ::: "memory")
#define BAR      __builtin_amdgcn_s_barrier()

__device__ __forceinline__ void gload_lds16(const u8* g, u8* l) {
  __builtin_amdgcn_global_load_lds(
      (const __attribute__((address_space(1))) u32*)g,
      (__attribute__((address_space(3))) u32*)l, 16, 0, 0);
}

// pack 4 floats -> 4 fp8(e4m3) bytes in a u32
__device__ __forceinline__ u32 pk4_fp8(float a, float b, float c, float d) {
  int w = __builtin_amdgcn_cvt_pk_fp8_f32(a, b, 0, 0);
  w = __builtin_amdgcn_cvt_pk_fp8_f32(c, d, w, 1);
  return (u32)w;
}

__device__ __forceinline__ u16 f2bf16(float x) {   // RNE f32->bf16
  u32 u = __builtin_bit_cast(u32, x);
  u32 r = u + 0x7fffu + ((u >> 16) & 1u);
  return (u16)(r >> 16);
}
__device__ __forceinline__ float bf2f(u16 v) {
  u32 u = ((u32)v) << 16;
  return __builtin_bit_cast(float, u);
}

// ---------------- k1: normalize E rows, emit fp8 operand tiles.
// EF3 (LINEAR S-read layout, r14-validated): addr = j*2048 + (tok>>4)*1024
//   + g*256 + (tok&15)*16 + h*8 + e  ->  E[tok][(2j+h)*32 + g*8 + e]
//   kflash S-read at j*2048 + hw*1024 + lane*16 (conflict-free, per-lane row=c).
// ET2 (NATURAL token order, r13-validated): addr = m*1024 + g*256 + c*16
//   + h*8 + e -> E[tok = g*8 + e][d = (2m+h)*16 + c]; read at n*1024+lane*16.
__global__ void kprep(const float* __restrict__ text,
                      u8* __restrict__ EF, u8* __restrict__ ET) {
  __shared__ u8 tile[32][528];
  int b = blockIdx.y, t = blockIdx.x;
  int tr = threadIdx.x;
  int row = tr >> 3, seg = tr & 7;          // 32 rows x 8 segs of 64 d
  const float* src = text + ((size_t)b * T_N + t * 32 + row) * D_N + seg * 64;
  float4 v[16];
  float ss = 0.f;
#pragma unroll
  for (int j = 0; j < 16; ++j) {
    v[j] = *(const float4*)(src + j * 4);
    ss += v[j].x*v[j].x + v[j].y*v[j].y + v[j].z*v[j].z + v[j].w*v[j].w;
  }
  ss += __shfl_xor(ss, 1); ss += __shfl_xor(ss, 2); ss += __shfl_xor(ss, 4);
  float inv = 1.f / fmaxf(sqrtf(ss), 1e-12f);
  u32 w[16];
#pragma unroll
  for (int j = 0; j < 16; ++j)
    w[j] = pk4_fp8(v[j].x*inv, v[j].y*inv, v[j].z*inv, v[j].w*inv);
  uint4* ldst = (uint4*)&tile[row][seg * 64];
#pragma unroll
  for (int j = 0; j < 4; ++j)
    ldst[j] = make_uint4(w[4*j], w[4*j+1], w[4*j+2], w[4*j+3]);
  __syncthreads();
  size_t tbase = ((size_t)(b * 64 + t)) << 14;
  {
    // EF3: thread covers (j, tok): j = tr>>5, tok = tr&31; 4 x 16B stores
    int j = tr >> 5, tok = tr & 31;
    u8* base = EF + tbase + j * 2048 + ((tok >> 4) << 10) + ((tok & 15) << 4);
#pragma unroll
    for (int g2 = 0; g2 < 4; ++g2) {
      uint2 h0 = *(const uint2*)&tile[tok][j*64 + g2*8];        // kk=2j
      uint2 h1 = *(const uint2*)&tile[tok][j*64 + 32 + g2*8];   // kk=2j+1
      *(uint4*)(base + g2 * 256) = make_uint4(h0.x, h0.y, h1.x, h1.y);
    }
  }
  {
    // ET2 (natural): thread covers 64B: m = tr>>4, g = (tr>>2)&3, c0 = (tr&3)*4
    int m = tr >> 4, g2 = (tr >> 2) & 3, c0 = (tr & 3) * 4;
    u32 acc[16];
#pragma unroll
    for (int ci = 0; ci < 4; ++ci)
#pragma unroll
      for (int h = 0; h < 2; ++h) {
        int c = c0 + ci, n = 2*m + h;
        u32 lo = 0, hi = 0;
#pragma unroll
        for (int e = 0; e < 4; ++e) lo |= (u32)tile[g2*8 + e][n*16 + c] << (8*e);
#pragma unroll
        for (int e = 0; e < 4; ++e) hi |= (u32)tile[g2*8 + 4 + e][n*16 + c] << (8*e);
        acc[ci*4 + h*2] = lo; acc[ci*4 + h*2 + 1] = hi;
      }
    uint4* dst = (uint4*)(ET + tbase + tr * 64);
#pragma unroll
    for (int q = 0; q < 4; ++q)
      dst[q] = make_uint4(acc[4*q], acc[4*q+1], acc[4*q+2], acc[4*q+3]);
  }
}

// ---------------- k2: flash attention, operand-shared + ONE-TILE-SKEW pipeline.
// 512 thr = 8 waves; block = 128 rows x 1024 cols. Iteration it does:
//   PV(t-1)  [plds[(t-1)&1] + etls[(t-1)%3] -- both ready at iter top]
//   S(t)     [els[t%3], P for 32 rows in regs (pf2)] -> softmax -> plds[t&1]
// One barrier per iteration; producer->consumer edge (p) crosses it.
// Buffers: E,ET 3-deep (stage E(t+2), ET(t+1) at iter top; parities distinct
// from all live readers); counted WAITV(4) steady (2/0 tail).
// LDS reads per wave per tile: S 8 b128, PV 2 b128 + 8 b64 (was 32 b128).
__launch_bounds__(512, 2)
__global__ void kflash(const float* __restrict__ pred,
                       const u8* __restrict__ EF, const u8* __restrict__ ET,
                       const int* __restrict__ mask,
                       u16* __restrict__ Opart, float* __restrict__ Lpart,
                       float* __restrict__ Dpart) {
  int b = blockIdx.x & 7;                 // batch -> XCD pin
  int rem = blockIdx.x >> 3;
  int rb = rem & 15, h = rem >> 4;        // 16 row-blocks of 128, 2 col halves
  int wid = threadIdx.x >> 6, lane = threadIdx.x & 63;
  int g = lane >> 4, c = lane & 15;
  int rq = wid >> 1, hw = wid & 1;        // row-quarter, token-half
  int Q0 = rq * 2;                        // wave's two 16-row tiles
  int t0 = h * 32;
  const int l16 = lane << 4;

  __shared__ u64 mbits[32];
  __shared__ __align__(16) u8 els[3][16384];
  __shared__ __align__(16) u8 etls[3][16384];
  __shared__ __align__(16) u8 plds[2][6144];   // 8 rowtiles x 16 rows x 48B
  __shared__ float Lbuf[2][128], Dbuf[2][128];

  const u8* EFb = EF + (((size_t)(b * 64)) << 14) + l16;
  const u8* ETb = ET + (((size_t)(b * 64)) << 14) + l16;

  auto stageE = [&](int buf, int t) {     // 2 gload per wave, 16 chunks
    size_t tb = ((size_t)t) << 14;
#pragma unroll
    for (int j = 0; j < 2; ++j) {
      int ch = wid * 2 + j;
      gload_lds16(EFb + tb + (ch << 10), &els[buf][ch << 10]);
    }
  };
  auto stageET = [&](int buf, int t) {
    size_t tb = ((size_t)t) << 14;
#pragma unroll
    for (int j = 0; j < 2; ++j) {
      int ch = wid * 2 + j;
      gload_lds16(ETb + tb + (ch << 10), &etls[buf][ch << 10]);
    }
  };

  for (int chunk = wid; chunk < 32; chunk += 8) {
    int col = chunk * 64 + lane;
    u64 bal = __ballot(mask[b * T_N + col] == 0);  // True mask = PAD
    if (lane == 0) mbits[chunk] = bal;
  }

  // prologue prefetch: E(t0)->els[0], ET(t0)->etls[0], E(t0+1)->els[1]
  stageE(0, t0); stageET(0, t0); stageE(1, t0 + 1);

  // P fragments for BOTH row-tiles of this wave's quarter (r13-validated).
  long pf2[2][16];
#pragma unroll
  for (int q = 0; q < 2; ++q) {
    int prow = rb * 128 + (Q0 + q) * 16 + c;
    const float* pr = pred + ((size_t)(b * T_N) + prow) * D_N;
    float ss = 0.f;
#pragma unroll
    for (int kk = 0; kk < 16; ++kk) {
      float4 v0 = *(const float4*)(pr + kk * 32 + g * 8);
      float4 v1 = *(const float4*)(pr + kk * 32 + g * 8 + 4);
      ss += v0.x*v0.x + v0.y*v0.y + v0.z*v0.z + v0.w*v0.w
          + v1.x*v1.x + v1.y*v1.y + v1.z*v1.z + v1.w*v1.w;
    }
    ss += __shfl_xor(ss, 16);
    ss += __shfl_xor(ss, 32);
    float inv = 1.f / fmaxf(sqrtf(ss), 1e-12f);
#pragma unroll
    for (int kk = 0; kk < 16; ++kk) {
      float4 v0 = *(const float4*)(pr + kk * 32 + g * 8);
      float4 v1 = *(const float4*)(pr + kk * 32 + g * 8 + 4);
      u32 lo = pk4_fp8(v0.x*inv, v0.y*inv, v0.z*inv, v0.w*inv);
      u32 hi = pk4_fp8(v1.x*inv, v1.y*inv, v1.z*inv, v1.w*inv);
      pf2[q][kk] = (long)(((u64)hi << 32) | lo);
    }
  }

  __syncthreads();   // mbits visible (staging handled by loop waits)

  f32x4 zero = {0.f, 0.f, 0.f, 0.f};
  f32x4 eh[8][4];                          // [rowtile q][d-tile n of 64-d slice]
#pragma unroll
  for (int q = 0; q < 8; ++q)
#pragma unroll
    for (int n = 0; n < 4; ++n) eh[q][n] = zero;
  float lsum[2] = {0.f, 0.f}, dsum[2] = {0.f, 0.f};

  const int sA_off = hw * 1024 + l16;      // S A-frag (linear: lane*16)
  const int pA_off = c * 48 + g * 8;       // PV A-frag (plds)
  const int pW_off = c * 48 + hw * 16 + g * 4;   // p-write (plds)

  int cE = 0, cE1 = 1, cE2 = 2;            // it%3, (it+1)%3, (it+2)%3

#pragma unroll 1
  for (int it = 0; it <= 32; ++it) {
    if (it < 31) { WAITV(4); } else if (it == 31) { WAITV(2); } else { WAITV(0); }
    WAITL0;                                // own plds writes visible pre-barrier
    BAR;

    // stages for future iterations (targets distinct from all live readers)
    if (it <= 30) stageET(cE1, t0 + it + 1);
    if (it <= 29) stageE(cE2, t0 + it + 2);

    // ---- PV(t-1): operands ready at iter top (plds written last iter) ----
    if (it >= 1) {
      const u8* et = &etls[cE2][0];        // (it+2)%3 == (it-1)%3
      const u8* pl = &plds[(it + 1) & 1][0];  // (it-1)&1
      longx2 bv0 = *(const longx2*)(et + (wid * 2) * 1024 + l16);
      longx2 bv1 = *(const longx2*)(et + (wid * 2 + 1) * 1024 + l16);
      __builtin_amdgcn_s_setprio(1);
#pragma unroll
      for (int q = 0; q < 8; ++q) {
        long af = *(const long*)(pl + q * 768 + pA_off);
        eh[q][0] = __builtin_amdgcn_mfma_f32_16x16x32_fp8_fp8(af, bv0[0], eh[q][0], 0, 0, 0);
        eh[q][1] = __builtin_amdgcn_mfma_f32_16x16x32_fp8_fp8(af, bv0[1], eh[q][1], 0, 0, 0);
        eh[q][2] = __builtin_amdgcn_mfma_f32_16x16x32_fp8_fp8(af, bv1[0], eh[q][2], 0, 0, 0);
        eh[q][3] = __builtin_amdgcn_mfma_f32_16x16x32_fp8_fp8(af, bv1[1], eh[q][3], 0, 0, 0);
      }
      __builtin_amdgcn_s_setprio(0);
    }

    // ---- S(t): S^T[16 toks (hw)][32 rows (Q0,Q0+1)] + softmax -> plds ----
    if (it < 32) {
      int t = t0 + it;
      const u8* el = &els[cE][0];
      f32x4 a00 = zero, a01 = zero, a10 = zero, a11 = zero;
      __builtin_amdgcn_s_setprio(1);
#pragma unroll
      for (int j = 0; j < 8; ++j) {
        longx2 av = *(const longx2*)(el + j * 2048 + sA_off);
        a00 = __builtin_amdgcn_mfma_f32_16x16x32_fp8_fp8(av[0], pf2[0][2*j],   a00, 0, 0, 0);
        a01 = __builtin_amdgcn_mfma_f32_16x16x32_fp8_fp8(av[1], pf2[0][2*j+1], a01, 0, 0, 0);
        a10 = __builtin_amdgcn_mfma_f32_16x16x32_fp8_fp8(av[0], pf2[1][2*j],   a10, 0, 0, 0);
        a11 = __builtin_amdgcn_mfma_f32_16x16x32_fp8_fp8(av[1], pf2[1][2*j+1], a11, 0, 0, 0);
      }
      __builtin_amdgcn_s_setprio(0);
      f32x4 st0 = a00 + a01, st1 = a10 + a11;  // tok hw*16+g*4+r, rows Q0/Q0+1

      int cb = t * 32;
      u64 mw = mbits[cb >> 6];
      u32 sh = (u32)(cb & 63) + hw * 16 + g * 4;
      u32 bits = (u32)(mw >> sh) & 0xf;
      float p0[4], p1[4];
#pragma unroll
      for (int r = 0; r < 4; ++r) {
        p0[r] = (bits >> r) & 1 ? __builtin_exp2f(fmaf(K1E, st0[r], -K2E)) : 0.f;
        p1[r] = (bits >> r) & 1 ? __builtin_exp2f(fmaf(K1E, st1[r], -K2E)) : 0.f;
        lsum[0] += p0[r]; dsum[0] += p0[r] * st0[r];
        lsum[1] += p1[r]; dsum[1] += p1[r] * st1[r];
      }
      u8* pw = &plds[it & 1][0];
      *(u32*)(pw + Q0 * 768 + pW_off)       = pk4_fp8(p0[0], p0[1], p0[2], p0[3]);
      *(u32*)(pw + (Q0 + 1) * 768 + pW_off) = pk4_fp8(p1[0], p1[1], p1[2], p1[3]);
    }

    cE  = (cE  == 2) ? 0 : cE  + 1;
    cE1 = (cE1 == 2) ? 0 : cE1 + 1;
    cE2 = (cE2 == 2) ? 0 : cE2 + 1;
  }

  // lsum/dsum: g-reduce in-wave, then cross token-half via LDS
#pragma unroll
  for (int q = 0; q < 2; ++q) {
    lsum[q] += __shfl_xor(lsum[q], 16); lsum[q] += __shfl_xor(lsum[q], 32);
    dsum[q] += __shfl_xor(dsum[q], 16); dsum[q] += __shfl_xor(dsum[q], 32);
  }
  if (g == 0) {
#pragma unroll
    for (int q = 0; q < 2; ++q) {
      Lbuf[hw][(Q0 + q) * 16 + c] = lsum[q];
      Dbuf[hw][(Q0 + q) * 16 + c] = dsum[q];
    }
  }

  // O write: wave wid owns cols wid*64..+64 for all 128 rows (r13-validated)
  u16* OP = Opart + (size_t)h * ((size_t)NROW * D_N);
  int bT = b * T_N + rb * 128;
#pragma unroll
  for (int q = 0; q < 8; ++q)
#pragma unroll
    for (int n = 0; n < 4; ++n) {
      int brow = bT + q * 16 + 4 * g;
      u16* orow = OP + (size_t)brow * D_N + wid * 64 + n * 16 + c;
#pragma unroll
      for (int r = 0; r < 4; ++r) orow[(size_t)r * D_N] = f2bf16(eh[q][n][r]);
    }
  __syncthreads();
  if (threadIdx.x < 128) {
    int row = threadIdx.x;
    Lpart[h * NROW + bT + row] = Lbuf[0][row] + Lbuf[1][row];
    Dpart[h * NROW + bT + row] = Dbuf[0][row] + Dbuf[1][row];
  }
}

// ---------------- k3: merge halves + cosine (no pred read) + block partials ----
__global__ void kcomb(const u16* __restrict__ Opart, const float* __restrict__ Lpart,
                      const float* __restrict__ Dpart,
                      float* __restrict__ pl, float* __restrict__ pw) {
  __shared__ float sl[8], swv[8];
  int tr = threadIdx.x;
  int row = blockIdx.x * 8 + (tr >> 5);
  int ln = tr & 31;
  float l = Lpart[row] + Lpart[NROW + row];
  float dot = Dpart[row] + Dpart[NROW + row];
  const u16* o0 = Opart + (size_t)row * D_N + ln * 16;
  const u16* o1 = o0 + (size_t)NROW * D_N;
  float e2 = 0.f;
#pragma unroll
  for (int q = 0; q < 2; ++q) {
    uint4 a0 = *(const uint4*)(o0 + q * 8);
    uint4 a1 = *(const uint4*)(o1 + q * 8);
    u32 w0[4] = {a0.x, a0.y, a0.z, a0.w};
    u32 w1[4] = {a1.x, a1.y, a1.z, a1.w};
#pragma unroll
    for (int j = 0; j < 8; ++j) {
      float f0 = bf2f((u16)((w0[j >> 1] >> ((j & 1) * 16)) & 0xffff));
      float f1 = bf2f((u16)((w1[j >> 1] >> ((j & 1) * 16)) & 0xffff));
      float ev = f0 + f1;
      e2 += ev * ev;
    }
  }
#pragma unroll
  for (int msk = 16; msk >= 1; msk >>= 1) e2 += __shfl_xor(e2, msk);
  if (ln == 0) {
    float w = (l > 0.f) ? 1.f : 0.f;
    float cosv = (l > 0.f) ? dot / fmaxf(sqrtf(e2), 1e-8f * l) : 0.f;
    sl[tr >> 5] = w * (1.f - cosv);
    swv[tr >> 5] = w;
  }
  __syncthreads();
  if (tr == 0) {
    float a = 0.f, b2 = 0.f;
#pragma unroll
    for (int i = 0; i < 8; ++i) { a += sl[i]; b2 += swv[i]; }
    pl[blockIdx.x] = a;
    pw[blockIdx.x] = b2;
  }
}

// ---------------- k4: deterministic final reduction (2048 partials) ----------------
__global__ void kreduce(const float* __restrict__ pl, const float* __restrict__ pw,
                        float* __restrict__ out) {
  __shared__ float sm[256], sw[256];
  float s = 0.f, w = 0.f;
  for (int i = threadIdx.x; i < NROW / 8; i += 256) { s += pl[i]; w += pw[i]; }
  sm[threadIdx.x] = s; sw[threadIdx.x] = w;
  __syncthreads();
#pragma unroll
  for (int st = 128; st >= 1; st >>= 1) {
    if ((int)threadIdx.x < st) {
      sm[threadIdx.x] += sm[threadIdx.x + st];
      sw[threadIdx.x] += sw[threadIdx.x + st];
    }
    __syncthreads();
  }
  if (threadIdx.x == 0) {
    float cnt = sw[0];
    float loss = (cnt > 0.f) ? sm[0] / fmaxf(cnt, 1.f) : 0.f;
    out[0] = loss;
    out[1] = (cnt > 0.f) ? 1.f - loss : 0.f;
  }
}

extern "C" void kernel_launch(void* const* d_in, const int* in_sizes, int n_in,
                              void* d_out, int out_size, void* d_ws, size_t ws_size,
                              hipStream_t stream) {
  const float* pred = (const float*)d_in[0];
  const float* text = (const float*)d_in[1];
  const int* mask = (const int*)d_in[2];
  char* ws = (char*)d_ws;
  const size_t EB8 = (size_t)B_N * T_N * D_N;          // 8MB per fp8 tensor
  const size_t OB = (size_t)NROW * D_N * 2;            // 16MB per bf16 O-half
  u8* EF = (u8*)ws;
  u8* ET = (u8*)(ws + EB8);
  u16* Opart = (u16*)(ws + 2 * EB8);                   // 2 halves = 32MB
  char* base2 = ws + 2 * EB8 + 2 * OB;
  float* Lpart = (float*)(base2);                      // 2*64KB
  float* Dpart = (float*)(base2 + 131072);             // 2*64KB
  float* pl = (float*)(base2 + 262144);
  float* pw = (float*)(base2 + 262144 + 16384);
  float* out = (float*)d_out;

  kprep<<<dim3(64, 8), dim3(256), 0, stream>>>(text, EF, ET);
  kflash<<<dim3(256), dim3(512), 0, stream>>>(pred, EF, ET, mask, Opart, Lpart, Dpart);
  kcomb<<<dim3(NROW / 8), dim3(256), 0, stream>>>(Opart, Lpart, Dpart, pl, pw);
  kreduce<<<dim3(1), dim3(256), 0, stream>>>(pl, pw, out);
}

// Round 16
// 93.763 us; speedup vs baseline: 1.2340x; 1.2340x over previous
//
#include <hip/hip_runtime.h>
#include <cstdint>

typedef float f32x4 __attribute__((ext_vector_type(4)));
typedef long longx2 __attribute__((ext_vector_type(2)));
typedef unsigned char u8;
typedef unsigned short u16;
typedef unsigned int u32;
typedef unsigned long long u64;

#define B_N 8
#define T_N 2048
#define D_N 512
#define NROW (B_N * T_N)    // 16384
// exp(TAU*s - 1) == exp2(K1*s - K2)
#define K1E 7.213475204444817f
#define K2E 1.4426950408889634f

#define WAITV(n) asm volatile("s_waitcnt vmcnt(" #n ")" ::: "memory")
#define BAR      __builtin_amdgcn_s_barrier()

__device__ __forceinline__ void gload_lds16(const u8* g, u8* l) {
  __builtin_amdgcn_global_load_lds(
      (const __attribute__((address_space(1))) u32*)g,
      (__attribute__((address_space(3))) u32*)l, 16, 0, 0);
}

// pack 4 floats -> 4 fp8(e4m3) bytes in a u32
__device__ __forceinline__ u32 pk4_fp8(float a, float b, float c, float d) {
  int w = __builtin_amdgcn_cvt_pk_fp8_f32(a, b, 0, 0);
  w = __builtin_amdgcn_cvt_pk_fp8_f32(c, d, w, 1);
  return (u32)w;
}

__device__ __forceinline__ u16 f2bf16(float x) {   // RNE f32->bf16
  u32 u = __builtin_bit_cast(u32, x);
  u32 r = u + 0x7fffu + ((u >> 16) & 1u);
  return (u16)(r >> 16);
}
__device__ __forceinline__ float bf2f(u16 v) {
  u32 u = ((u32)v) << 16;
  return __builtin_bit_cast(float, u);
}

// ---------------- k1: normalize E rows, emit fp8 operand tiles (r14-validated).
// EF3 (LINEAR S-read layout): addr = j*2048 + (tok>>4)*1024 + g*256
//      + (tok&15)*16 + h*8 + e  ->  E[tok][(2j+h)*32 + g*8 + e]
// ET2 (token-PERMUTED sigma): addr = m*1024 + g*256 + c*16 + h*8 + e ->
//      lo-word toks 4g..4g+3, hi-word toks 16+4g..16+4g+3, d=(2m+h)*16+c
__global__ void kprep(const float* __restrict__ text,
                      u8* __restrict__ EF, u8* __restrict__ ET) {
  __shared__ u8 tile[32][528];
  int b = blockIdx.y, t = blockIdx.x;
  int tr = threadIdx.x;
  int row = tr >> 3, seg = tr & 7;          // 32 rows x 8 segs of 64 d
  const float* src = text + ((size_t)b * T_N + t * 32 + row) * D_N + seg * 64;
  float4 v[16];
  float ss = 0.f;
#pragma unroll
  for (int j = 0; j < 16; ++j) {
    v[j] = *(const float4*)(src + j * 4);
    ss += v[j].x*v[j].x + v[j].y*v[j].y + v[j].z*v[j].z + v[j].w*v[j].w;
  }
  ss += __shfl_xor(ss, 1); ss += __shfl_xor(ss, 2); ss += __shfl_xor(ss, 4);
  float inv = 1.f / fmaxf(sqrtf(ss), 1e-12f);
  u32 w[16];
#pragma unroll
  for (int j = 0; j < 16; ++j)
    w[j] = pk4_fp8(v[j].x*inv, v[j].y*inv, v[j].z*inv, v[j].w*inv);
  uint4* ldst = (uint4*)&tile[row][seg * 64];
#pragma unroll
  for (int j = 0; j < 4; ++j)
    ldst[j] = make_uint4(w[4*j], w[4*j+1], w[4*j+2], w[4*j+3]);
  __syncthreads();
  size_t tbase = ((size_t)(b * 64 + t)) << 14;
  {
    // EF3: j = tr>>5, tok = tr&31; 4 x 16B stores
    int j = tr >> 5, tok = tr & 31;
    u8* base = EF + tbase + j * 2048 + ((tok >> 4) << 10) + ((tok & 15) << 4);
#pragma unroll
    for (int g2 = 0; g2 < 4; ++g2) {
      uint2 h0 = *(const uint2*)&tile[tok][j*64 + g2*8];        // kk=2j
      uint2 h1 = *(const uint2*)&tile[tok][j*64 + 32 + g2*8];   // kk=2j+1
      *(uint4*)(base + g2 * 256) = make_uint4(h0.x, h0.y, h1.x, h1.y);
    }
  }
  {
    // ET2 sigma: m = tr>>4, g = (tr>>2)&3, c0 = (tr&3)*4
    int m = tr >> 4, g2 = (tr >> 2) & 3, c0 = (tr & 3) * 4;
    u32 acc[16];
#pragma unroll
    for (int ci = 0; ci < 4; ++ci)
#pragma unroll
      for (int h = 0; h < 2; ++h) {
        int c = c0 + ci, n = 2*m + h;
        u32 lo = 0, hi = 0;
#pragma unroll
        for (int e = 0; e < 4; ++e) lo |= (u32)tile[g2*4 + e][n*16 + c] << (8*e);
#pragma unroll
        for (int e = 0; e < 4; ++e) hi |= (u32)tile[16 + g2*4 + e][n*16 + c] << (8*e);
        acc[ci*4 + h*2] = lo; acc[ci*4 + h*2 + 1] = hi;
      }
    uint4* dst = (uint4*)(ET + tbase + tr * 64);
#pragma unroll
    for (int q = 0; q < 4; ++q)
      dst[q] = make_uint4(acc[4*q], acc[4*q+1], acc[4*q+2], acc[4*q+3]);
  }
}

// ---------------- k2: FUSED flash attention + cosine loss.
// 512 thr = 8 waves: waves 0-3 = column-half 0, waves 4-7 = half 1; both
// groups cover the SAME 64 rows (grid 256 = 8 batch x 32 row-blocks, 1
// block/CU). Main loop per wave = r14's proven body (linear conflict-free
// LDS reads, read-ahead ping-pong, counted WAITV(4), 2 barriers/tile).
// Epilogue: group 1 dumps its O-half (bf16) into the dead staging LDS;
// group 0 adds its own registers, computes |O|^2, cos via lsum/dsum, and
// emits ONE (loss, weight) partial per block. No Opart, no kcomb.
__launch_bounds__(512, 1)
__global__ void kflash(const float* __restrict__ pred,
                       const u8* __restrict__ EF, const u8* __restrict__ ET,
                       const int* __restrict__ mask,
                       float* __restrict__ pl, float* __restrict__ pw) {
  int b = blockIdx.x & 7, rb = blockIdx.x >> 3;   // batch (XCD pin), row-block
  int wid = threadIdx.x >> 6, lane = threadIdx.x & 63;
  int g = lane >> 4, c = lane & 15;
  int h = wid >> 2, wg = wid & 3;         // column-half group, wave-in-group
  int row0 = rb * 64 + wg * 16;
  int t0 = h * 32;
  const int l16 = lane << 4;

  __shared__ __align__(16) u8 smem[133120];
  u8* els  = smem + h * 32768;            // [buf][16384] per group
  u8* etls = smem + 65536 + h * 32768;
  u64* mbits = (u64*)(smem + 131072);     // 256 B
  float* Lb = (float*)(smem + 131328);    // [2][64]
  float* Db = (float*)(smem + 131840);    // [2][64]
  float* slb = (float*)(smem + 132352);   // [4]
  float* swb = (float*)(smem + 132368);   // [4]
  u16* obuf = (u16*)smem;                 // ALIAS after loop: [512][68] bf16

  const u8* EFb = EF + (((size_t)(b * 64)) << 14) + l16;
  const u8* ETb = ET + (((size_t)(b * 64)) << 14) + l16;

  auto stageE = [&](int buf, int t) {     // 4 gload per wave (group tile 16KB)
    size_t tb = ((size_t)t) << 14;
#pragma unroll
    for (int j = 0; j < 4; ++j) {
      int ch = wg * 4 + j;
      gload_lds16(EFb + tb + (ch << 10), els + buf * 16384 + (ch << 10));
    }
  };
  auto stageET = [&](int buf, int t) {
    size_t tb = ((size_t)t) << 14;
#pragma unroll
    for (int j = 0; j < 4; ++j) {
      int ch = wg * 4 + j;
      gload_lds16(ETb + tb + (ch << 10), etls + buf * 16384 + (ch << 10));
    }
  };

  for (int chunk = wid; chunk < 32; chunk += 8) {
    int col = chunk * 64 + lane;
    u64 bal = __ballot(mask[b * T_N + col] == 0);  // True mask = PAD
    if (lane == 0) mbits[chunk] = bal;
  }

  // prologue prefetch: E(t0), ET(t0), E(t0+1)  (group-local tiles)
  stageE(0, t0); stageET(0, t0); stageE(1, t0 + 1);

  // P fragments: two-pass fp32 normalize -> fp8 (r14 verbatim)
  long pf[16];
  {
    int prow = row0 + c;
    const float* pr = pred + ((size_t)(b * T_N) + prow) * D_N;
    float ss = 0.f;
#pragma unroll
    for (int kk = 0; kk < 16; ++kk) {
      float4 v0 = *(const float4*)(pr + kk * 32 + g * 8);
      float4 v1 = *(const float4*)(pr + kk * 32 + g * 8 + 4);
      ss += v0.x*v0.x + v0.y*v0.y + v0.z*v0.z + v0.w*v0.w
          + v1.x*v1.x + v1.y*v1.y + v1.z*v1.z + v1.w*v1.w;
    }
    ss += __shfl_xor(ss, 16);
    ss += __shfl_xor(ss, 32);
    float inv = 1.f / fmaxf(sqrtf(ss), 1e-12f);
#pragma unroll
    for (int kk = 0; kk < 16; ++kk) {
      float4 v0 = *(const float4*)(pr + kk * 32 + g * 8);
      float4 v1 = *(const float4*)(pr + kk * 32 + g * 8 + 4);
      u32 lo = pk4_fp8(v0.x*inv, v0.y*inv, v0.z*inv, v0.w*inv);
      u32 hi = pk4_fp8(v1.x*inv, v1.y*inv, v1.z*inv, v1.w*inv);
      pf[kk] = (long)(((u64)hi << 32) | lo);
    }
  }

  __syncthreads();   // mbits visible; prologue staging drained (vmcnt=0)

  f32x4 zero = {0.f, 0.f, 0.f, 0.f};
  f32x4 eh[32];
#pragma unroll
  for (int n = 0; n < 32; ++n) eh[n] = zero;
  float lsum = 0.f, dsum = 0.f;            // per-lane: q-row c partials

#pragma unroll 1
  for (int tt = 0; tt < 32; ++tt) {
    int cur = tt & 1;
    // steady outstanding at top: E(t)[4] + ET(t)[4] + E(t+1)[4];
    // WAITV(4) drains E(t),ET(t); leaves E(t+1) in flight.
    if (tt < 31) { WAITV(4); } else { WAITV(0); }
    BAR;

    // ---- S phase (+ issue ET(t+1)) ----
    if (tt < 31) stageET(cur ^ 1, t0 + tt + 1);
    const u8* el = els + cur * 16384;
    longx2 rS0[2], rS1[2];                // read-ahead ping-pong
    rS0[0] = *(const longx2*)(el + l16);
    rS1[0] = *(const longx2*)(el + 1024 + l16);
    f32x4 a00 = zero, a01 = zero, a10 = zero, a11 = zero;
    __builtin_amdgcn_s_setprio(1);
#pragma unroll
    for (int j = 0; j < 8; ++j) {
      int pp = j & 1;
      if (j < 7) {
        rS0[pp ^ 1] = *(const longx2*)(el + (j + 1) * 2048 + l16);
        rS1[pp ^ 1] = *(const longx2*)(el + (j + 1) * 2048 + 1024 + l16);
      }
      a00 = __builtin_amdgcn_mfma_f32_16x16x32_fp8_fp8(rS0[pp][0], pf[2*j],   a00, 0, 0, 0);
      a01 = __builtin_amdgcn_mfma_f32_16x16x32_fp8_fp8(rS0[pp][1], pf[2*j+1], a01, 0, 0, 0);
      a10 = __builtin_amdgcn_mfma_f32_16x16x32_fp8_fp8(rS1[pp][0], pf[2*j],   a10, 0, 0, 0);
      a11 = __builtin_amdgcn_mfma_f32_16x16x32_fp8_fp8(rS1[pp][1], pf[2*j+1], a11, 0, 0, 0);
    }
    __builtin_amdgcn_s_setprio(0);
    f32x4 st0 = a00 + a01, st1 = a10 + a11;  // st0: toks g*4+r, st1: 16+g*4+r
    BAR;                                  // all group waves done with E(t)

    // ---- softmax + PV (+ issue E(t+2)) ----
    if (tt < 30) stageE(cur, t0 + tt + 2);
    int c0 = (t0 + tt) * 32;
    u64 mw = mbits[c0 >> 6];
    u32 sh0 = (c0 & 63) + g * 4;
    u32 bits0 = (u32)(mw >> sh0) & 0xf;
    u32 bits1 = (u32)(mw >> (sh0 + 16)) & 0xf;
    float p0[4], p1[4];
#pragma unroll
    for (int r = 0; r < 4; ++r) {
      p0[r] = (bits0 >> r) & 1 ? __builtin_exp2f(fmaf(K1E, st0[r], -K2E)) : 0.f;
      p1[r] = (bits1 >> r) & 1 ? __builtin_exp2f(fmaf(K1E, st1[r], -K2E)) : 0.f;
      lsum += p0[r] + p1[r];
      dsum += p0[r] * st0[r] + p1[r] * st1[r];   // dot(P_hat, O) partial
    }
    u32 lo = pk4_fp8(p0[0], p0[1], p0[2], p0[3]);  // toks 4g..4g+3
    u32 hi = pk4_fp8(p1[0], p1[1], p1[2], p1[3]);  // toks 16+4g..16+4g+3
    long af = (long)(((u64)hi << 32) | lo);

    const u8* et = etls + cur * 16384;
    longx2 rV[2];
    rV[0] = *(const longx2*)(et + l16);
    __builtin_amdgcn_s_setprio(1);
#pragma unroll
    for (int m = 0; m < 16; ++m) {
      int pp = m & 1;
      if (m < 15) rV[pp ^ 1] = *(const longx2*)(et + (m + 1) * 1024 + l16);
      eh[2*m]   = __builtin_amdgcn_mfma_f32_16x16x32_fp8_fp8(af, rV[pp][0], eh[2*m],   0, 0, 0);
      eh[2*m+1] = __builtin_amdgcn_mfma_f32_16x16x32_fp8_fp8(af, rV[pp][1], eh[2*m+1], 0, 0, 0);
    }
    __builtin_amdgcn_s_setprio(0);
    // next iter-top BAR covers etls[cur] cross-wave hazard
  }

  // ---- fused epilogue ----
  // lsum/dsum: reduce over g (row = c within wave's 16 rows)
  lsum += __shfl_xor(lsum, 16);
  lsum += __shfl_xor(lsum, 32);
  dsum += __shfl_xor(dsum, 16);
  dsum += __shfl_xor(dsum, 32);
  if (g == 0) {
    Lb[h * 64 + wg * 16 + c] = lsum;
    Db[h * 64 + wg * 16 + c] = dsum;
  }
  __syncthreads();   // all loop LDS reads done; staging drained; Lb/Db visible

  // group 1 dumps O-half into dead staging LDS: obuf[d][row], row-pad 68
  if (h == 1) {
#pragma unroll
    for (int n = 0; n < 32; ++n) {
      u32 lo2 = (u32)f2bf16(eh[n][0]) | ((u32)f2bf16(eh[n][1]) << 16);
      u32 hi2 = (u32)f2bf16(eh[n][2]) | ((u32)f2bf16(eh[n][3]) << 16);
      *(uint2*)&obuf[(n * 16 + c) * 68 + wg * 16 + g * 4] = make_uint2(lo2, hi2);
    }
  }
  __syncthreads();

  float cl = 0.f, wl = 0.f;
  if (h == 0) {
    float e2a[4] = {0.f, 0.f, 0.f, 0.f};
#pragma unroll
    for (int n = 0; n < 32; ++n) {
      uint2 v = *(const uint2*)&obuf[(n * 16 + c) * 68 + wg * 16 + g * 4];
      float s0 = eh[n][0] + bf2f((u16)(v.x & 0xffff));
      float s1 = eh[n][1] + bf2f((u16)(v.x >> 16));
      float s2 = eh[n][2] + bf2f((u16)(v.y & 0xffff));
      float s3 = eh[n][3] + bf2f((u16)(v.y >> 16));
      e2a[0] += s0 * s0; e2a[1] += s1 * s1;
      e2a[2] += s2 * s2; e2a[3] += s3 * s3;
    }
#pragma unroll
    for (int r = 0; r < 4; ++r) {
      e2a[r] += __shfl_xor(e2a[r], 1);
      e2a[r] += __shfl_xor(e2a[r], 2);
      e2a[r] += __shfl_xor(e2a[r], 4);
      e2a[r] += __shfl_xor(e2a[r], 8);
    }
    if (c == 0) {
#pragma unroll
      for (int r = 0; r < 4; ++r) {
        int row = wg * 16 + g * 4 + r;
        float l = Lb[row] + Lb[64 + row];
        float dot = Db[row] + Db[64 + row];
        float w = (l > 0.f) ? 1.f : 0.f;
        float cosv = (l > 0.f) ? dot / fmaxf(sqrtf(e2a[r]), 1e-8f * l) : 0.f;
        cl += w * (1.f - cosv);
        wl += w;
      }
    }
    cl += __shfl_xor(cl, 16); cl += __shfl_xor(cl, 32);
    wl += __shfl_xor(wl, 16); wl += __shfl_xor(wl, 32);
    if (lane == 0) { slb[wg] = cl; swb[wg] = wl; }
  }
  __syncthreads();
  if (threadIdx.x == 0) {
    pl[blockIdx.x] = slb[0] + slb[1] + slb[2] + slb[3];
    pw[blockIdx.x] = swb[0] + swb[1] + swb[2] + swb[3];
  }
}

// ---------------- k3: deterministic final reduction (256 partials) ----------------
__global__ void kreduce(const float* __restrict__ pl, const float* __restrict__ pw,
                        float* __restrict__ out) {
  __shared__ float sm[256], sw[256];
  int t = threadIdx.x;
  sm[t] = pl[t]; sw[t] = pw[t];
  __syncthreads();
#pragma unroll
  for (int st = 128; st >= 1; st >>= 1) {
    if (t < st) { sm[t] += sm[t + st]; sw[t] += sw[t + st]; }
    __syncthreads();
  }
  if (t == 0) {
    float cnt = sw[0];
    float loss = (cnt > 0.f) ? sm[0] / fmaxf(cnt, 1.f) : 0.f;
    out[0] = loss;
    out[1] = (cnt > 0.f) ? 1.f - loss : 0.f;
  }
}

extern "C" void kernel_launch(void* const* d_in, const int* in_sizes, int n_in,
                              void* d_out, int out_size, void* d_ws, size_t ws_size,
                              hipStream_t stream) {
  const float* pred = (const float*)d_in[0];
  const float* text = (const float*)d_in[1];
  const int* mask = (const int*)d_in[2];
  char* ws = (char*)d_ws;
  const size_t EB8 = (size_t)B_N * T_N * D_N;          // 8MB per fp8 tensor
  u8* EF = (u8*)ws;
  u8* ET = (u8*)(ws + EB8);
  float* pl = (float*)(ws + 2 * EB8);
  float* pw = (float*)(ws + 2 * EB8 + 4096);
  float* out = (float*)d_out;

  kprep<<<dim3(64, 8), dim3(256), 0, stream>>>(text, EF, ET);
  kflash<<<dim3(256), dim3(512), 0, stream>>>(pred, EF, ET, mask, pl, pw);
  kreduce<<<dim3(1), dim3(256), 0, stream>>>(pl, pw, out);
}

// Round 17
// 90.040 us; speedup vs baseline: 1.2850x; 1.0413x over previous
//
#include <hip/hip_runtime.h>
#include <cstdint>

typedef float f32x4 __attribute__((ext_vector_type(4)));
typedef long longx2 __attribute__((ext_vector_type(2)));
typedef unsigned char u8;
typedef unsigned short u16;
typedef unsigned int u32;
typedef unsigned long long u64;

#define B_N 8
#define T_N 2048
#define D_N 512
#define NROW (B_N * T_N)    // 16384
// exp(TAU*s - 1) == exp2(K1*s - K2)
#define K1E 7.213475204444817f
#define K2E 1.4426950408889634f

#define WAITV(n) asm volatile("s_waitcnt vmcnt(" #n ")" ::: "memory")
#define BAR      __builtin_amdgcn_s_barrier()

__device__ __forceinline__ void gload_lds16(const u8* g, u8* l) {
  __builtin_amdgcn_global_load_lds(
      (const __attribute__((address_space(1))) u32*)g,
      (__attribute__((address_space(3))) u32*)l, 16, 0, 0);
}

// pack 4 floats -> 4 fp8(e4m3) bytes in a u32
__device__ __forceinline__ u32 pk4_fp8(float a, float b, float c, float d) {
  int w = __builtin_amdgcn_cvt_pk_fp8_f32(a, b, 0, 0);
  w = __builtin_amdgcn_cvt_pk_fp8_f32(c, d, w, 1);
  return (u32)w;
}

__device__ __forceinline__ u16 f2bf16(float x) {   // RNE f32->bf16
  u32 u = __builtin_bit_cast(u32, x);
  u32 r = u + 0x7fffu + ((u >> 16) & 1u);
  return (u16)(r >> 16);
}
__device__ __forceinline__ float bf2f(u16 v) {
  u32 u = ((u32)v) << 16;
  return __builtin_bit_cast(float, u);
}

// ---------------- k1: normalize E rows, emit fp8 operand tiles (r14-validated).
// EF3 (LINEAR S-read layout): addr = j*2048 + (tok>>4)*1024 + g*256
//      + (tok&15)*16 + h*8 + e  ->  E[tok][(2j+h)*32 + g*8 + e]
// ET2 (token-PERMUTED sigma): addr = m*1024 + g*256 + c*16 + h*8 + e ->
//      lo-word toks 4g..4g+3, hi-word toks 16+4g..16+4g+3, d=(2m+h)*16+c
__global__ void kprep(const float* __restrict__ text,
                      u8* __restrict__ EF, u8* __restrict__ ET) {
  __shared__ u8 tile[32][528];
  int b = blockIdx.y, t = blockIdx.x;
  int tr = threadIdx.x;
  int row = tr >> 3, seg = tr & 7;          // 32 rows x 8 segs of 64 d
  const float* src = text + ((size_t)b * T_N + t * 32 + row) * D_N + seg * 64;
  float4 v[16];
  float ss = 0.f;
#pragma unroll
  for (int j = 0; j < 16; ++j) {
    v[j] = *(const float4*)(src + j * 4);
    ss += v[j].x*v[j].x + v[j].y*v[j].y + v[j].z*v[j].z + v[j].w*v[j].w;
  }
  ss += __shfl_xor(ss, 1); ss += __shfl_xor(ss, 2); ss += __shfl_xor(ss, 4);
  float inv = 1.f / fmaxf(sqrtf(ss), 1e-12f);
  u32 w[16];
#pragma unroll
  for (int j = 0; j < 16; ++j)
    w[j] = pk4_fp8(v[j].x*inv, v[j].y*inv, v[j].z*inv, v[j].w*inv);
  uint4* ldst = (uint4*)&tile[row][seg * 64];
#pragma unroll
  for (int j = 0; j < 4; ++j)
    ldst[j] = make_uint4(w[4*j], w[4*j+1], w[4*j+2], w[4*j+3]);
  __syncthreads();
  size_t tbase = ((size_t)(b * 64 + t)) << 14;
  {
    // EF3: j = tr>>5, tok = tr&31; 4 x 16B stores
    int j = tr >> 5, tok = tr & 31;
    u8* base = EF + tbase + j * 2048 + ((tok >> 4) << 10) + ((tok & 15) << 4);
#pragma unroll
    for (int g2 = 0; g2 < 4; ++g2) {
      uint2 h0 = *(const uint2*)&tile[tok][j*64 + g2*8];        // kk=2j
      uint2 h1 = *(const uint2*)&tile[tok][j*64 + 32 + g2*8];   // kk=2j+1
      *(uint4*)(base + g2 * 256) = make_uint4(h0.x, h0.y, h1.x, h1.y);
    }
  }
  {
    // ET2 sigma: m = tr>>4, g = (tr>>2)&3, c0 = (tr&3)*4
    int m = tr >> 4, g2 = (tr >> 2) & 3, c0 = (tr & 3) * 4;
    u32 acc[16];
#pragma unroll
    for (int ci = 0; ci < 4; ++ci)
#pragma unroll
      for (int h = 0; h < 2; ++h) {
        int c = c0 + ci, n = 2*m + h;
        u32 lo = 0, hi = 0;
#pragma unroll
        for (int e = 0; e < 4; ++e) lo |= (u32)tile[g2*4 + e][n*16 + c] << (8*e);
#pragma unroll
        for (int e = 0; e < 4; ++e) hi |= (u32)tile[16 + g2*4 + e][n*16 + c] << (8*e);
        acc[ci*4 + h*2] = lo; acc[ci*4 + h*2 + 1] = hi;
      }
    uint4* dst = (uint4*)(ET + tbase + tr * 64);
#pragma unroll
    for (int q = 0; q < 4; ++q)
      dst[q] = make_uint4(acc[4*q], acc[4*q+1], acc[4*q+2], acc[4*q+3]);
  }
}

// ---------------- k2: FUSED flash attention + cosine loss, ONE barrier/tile.
// 512 thr = 8 waves: waves 0-3 = column-half 0, waves 4-7 = half 1; both
// groups cover the SAME 64 rows (grid 256 = 8 batch x 32 row-blocks).
// Staging at distance 1, parity (t+1)&1: WAR on that buffer (last read at
// iter t-1) is ordered by the single top-of-iteration barrier; RAW by the
// top WAITV(0) (loads are a full iteration old). Waves drift a phase ->
// cross-wave LDS/MFMA overlap; setprio arbitrates.
__launch_bounds__(512, 1)
__global__ void kflash(const float* __restrict__ pred,
                       const u8* __restrict__ EF, const u8* __restrict__ ET,
                       const int* __restrict__ mask,
                       float* __restrict__ pl, float* __restrict__ pw) {
  int b = blockIdx.x & 7, rb = blockIdx.x >> 3;   // batch (XCD pin), row-block
  int wid = threadIdx.x >> 6, lane = threadIdx.x & 63;
  int g = lane >> 4, c = lane & 15;
  int h = wid >> 2, wg = wid & 3;         // column-half group, wave-in-group
  int row0 = rb * 64 + wg * 16;
  int t0 = h * 32;
  const int l16 = lane << 4;

  __shared__ __align__(16) u8 smem[133120];
  u8* els  = smem + h * 32768;            // [buf][16384] per group
  u8* etls = smem + 65536 + h * 32768;
  u64* mbits = (u64*)(smem + 131072);     // 256 B
  float* Lb = (float*)(smem + 131328);    // [2][64]
  float* Db = (float*)(smem + 131840);    // [2][64]
  float* slb = (float*)(smem + 132352);   // [4]
  float* swb = (float*)(smem + 132368);   // [4]
  u16* obuf = (u16*)smem;                 // ALIAS after loop: [512][68] bf16

  const u8* EFb = EF + (((size_t)(b * 64)) << 14) + l16;
  const u8* ETb = ET + (((size_t)(b * 64)) << 14) + l16;

  auto stageE = [&](int buf, int t) {     // 4 gload per wave (group tile 16KB)
    size_t tb = ((size_t)t) << 14;
#pragma unroll
    for (int j = 0; j < 4; ++j) {
      int ch = wg * 4 + j;
      gload_lds16(EFb + tb + (ch << 10), els + buf * 16384 + (ch << 10));
    }
  };
  auto stageET = [&](int buf, int t) {
    size_t tb = ((size_t)t) << 14;
#pragma unroll
    for (int j = 0; j < 4; ++j) {
      int ch = wg * 4 + j;
      gload_lds16(ETb + tb + (ch << 10), etls + buf * 16384 + (ch << 10));
    }
  };

  for (int chunk = wid; chunk < 32; chunk += 8) {
    int col = chunk * 64 + lane;
    u64 bal = __ballot(mask[b * T_N + col] == 0);  // True mask = PAD
    if (lane == 0) mbits[chunk] = bal;
  }

  // prologue prefetch: E(t0), ET(t0) into buf 0
  stageE(0, t0); stageET(0, t0);

  // P fragments: two-pass fp32 normalize -> fp8 (r14 verbatim)
  long pf[16];
  {
    int prow = row0 + c;
    const float* pr = pred + ((size_t)(b * T_N) + prow) * D_N;
    float ss = 0.f;
#pragma unroll
    for (int kk = 0; kk < 16; ++kk) {
      float4 v0 = *(const float4*)(pr + kk * 32 + g * 8);
      float4 v1 = *(const float4*)(pr + kk * 32 + g * 8 + 4);
      ss += v0.x*v0.x + v0.y*v0.y + v0.z*v0.z + v0.w*v0.w
          + v1.x*v1.x + v1.y*v1.y + v1.z*v1.z + v1.w*v1.w;
    }
    ss += __shfl_xor(ss, 16);
    ss += __shfl_xor(ss, 32);
    float inv = 1.f / fmaxf(sqrtf(ss), 1e-12f);
#pragma unroll
    for (int kk = 0; kk < 16; ++kk) {
      float4 v0 = *(const float4*)(pr + kk * 32 + g * 8);
      float4 v1 = *(const float4*)(pr + kk * 32 + g * 8 + 4);
      u32 lo = pk4_fp8(v0.x*inv, v0.y*inv, v0.z*inv, v0.w*inv);
      u32 hi = pk4_fp8(v1.x*inv, v1.y*inv, v1.z*inv, v1.w*inv);
      pf[kk] = (long)(((u64)hi << 32) | lo);
    }
  }

  __syncthreads();   // mbits visible; prologue staging drained (vmcnt=0)

  f32x4 zero = {0.f, 0.f, 0.f, 0.f};
  f32x4 eh[32];
#pragma unroll
  for (int n = 0; n < 32; ++n) eh[n] = zero;
  float lsum = 0.f, dsum = 0.f;            // per-lane: q-row c partials

#pragma unroll 1
  for (int tt = 0; tt < 32; ++tt) {
    int cur = tt & 1;
    // outstanding: E(t)[4]+ET(t)[4] issued at iter t-1 top (a full iteration
    // ago, L2-resident -> drain ~free). Single barrier orders last iter's
    // reads of buf[cur^1] before this iter's staging writes to it.
    WAITV(0);
    BAR;
    if (tt < 31) { stageET(cur ^ 1, t0 + tt + 1); stageE(cur ^ 1, t0 + tt + 1); }

    // ---- S phase ----
    const u8* el = els + cur * 16384;
    longx2 rS0[2], rS1[2];                // read-ahead ping-pong
    rS0[0] = *(const longx2*)(el + l16);
    rS1[0] = *(const longx2*)(el + 1024 + l16);
    f32x4 a00 = zero, a01 = zero, a10 = zero, a11 = zero;
    __builtin_amdgcn_s_setprio(1);
#pragma unroll
    for (int j = 0; j < 8; ++j) {
      int pp = j & 1;
      if (j < 7) {
        rS0[pp ^ 1] = *(const longx2*)(el + (j + 1) * 2048 + l16);
        rS1[pp ^ 1] = *(const longx2*)(el + (j + 1) * 2048 + 1024 + l16);
      }
      a00 = __builtin_amdgcn_mfma_f32_16x16x32_fp8_fp8(rS0[pp][0], pf[2*j],   a00, 0, 0, 0);
      a01 = __builtin_amdgcn_mfma_f32_16x16x32_fp8_fp8(rS0[pp][1], pf[2*j+1], a01, 0, 0, 0);
      a10 = __builtin_amdgcn_mfma_f32_16x16x32_fp8_fp8(rS1[pp][0], pf[2*j],   a10, 0, 0, 0);
      a11 = __builtin_amdgcn_mfma_f32_16x16x32_fp8_fp8(rS1[pp][1], pf[2*j+1], a11, 0, 0, 0);
    }
    __builtin_amdgcn_s_setprio(0);
    f32x4 st0 = a00 + a01, st1 = a10 + a11;  // st0: toks g*4+r, st1: 16+g*4+r

    // ---- softmax ----
    int c0 = (t0 + tt) * 32;
    u64 mw = mbits[c0 >> 6];
    u32 sh0 = (c0 & 63) + g * 4;
    u32 bits0 = (u32)(mw >> sh0) & 0xf;
    u32 bits1 = (u32)(mw >> (sh0 + 16)) & 0xf;
    float p0[4], p1[4];
#pragma unroll
    for (int r = 0; r < 4; ++r) {
      p0[r] = (bits0 >> r) & 1 ? __builtin_exp2f(fmaf(K1E, st0[r], -K2E)) : 0.f;
      p1[r] = (bits1 >> r) & 1 ? __builtin_exp2f(fmaf(K1E, st1[r], -K2E)) : 0.f;
      lsum += p0[r] + p1[r];
      dsum += p0[r] * st0[r] + p1[r] * st1[r];   // dot(P_hat, O) partial
    }
    u32 lo = pk4_fp8(p0[0], p0[1], p0[2], p0[3]);  // toks 4g..4g+3
    u32 hi = pk4_fp8(p1[0], p1[1], p1[2], p1[3]);  // toks 16+4g..16+4g+3
    long af = (long)(((u64)hi << 32) | lo);

    // ---- PV phase ----
    const u8* et = etls + cur * 16384;
    longx2 rV[2];
    rV[0] = *(const longx2*)(et + l16);
    __builtin_amdgcn_s_setprio(1);
#pragma unroll
    for (int m = 0; m < 16; ++m) {
      int pp = m & 1;
      if (m < 15) rV[pp ^ 1] = *(const longx2*)(et + (m + 1) * 1024 + l16);
      eh[2*m]   = __builtin_amdgcn_mfma_f32_16x16x32_fp8_fp8(af, rV[pp][0], eh[2*m],   0, 0, 0);
      eh[2*m+1] = __builtin_amdgcn_mfma_f32_16x16x32_fp8_fp8(af, rV[pp][1], eh[2*m+1], 0, 0, 0);
    }
    __builtin_amdgcn_s_setprio(0);
    // next iter-top BAR covers all cross-wave hazards
  }

  // ---- fused epilogue ----
  lsum += __shfl_xor(lsum, 16);
  lsum += __shfl_xor(lsum, 32);
  dsum += __shfl_xor(dsum, 16);
  dsum += __shfl_xor(dsum, 32);
  if (g == 0) {
    Lb[h * 64 + wg * 16 + c] = lsum;
    Db[h * 64 + wg * 16 + c] = dsum;
  }
  __syncthreads();   // all loop LDS reads done; staging drained; Lb/Db visible

  // group 1 dumps O-half into dead staging LDS: obuf[d][row], row-pad 68
  if (h == 1) {
#pragma unroll
    for (int n = 0; n < 32; ++n) {
      u32 lo2 = (u32)f2bf16(eh[n][0]) | ((u32)f2bf16(eh[n][1]) << 16);
      u32 hi2 = (u32)f2bf16(eh[n][2]) | ((u32)f2bf16(eh[n][3]) << 16);
      *(uint2*)&obuf[(n * 16 + c) * 68 + wg * 16 + g * 4] = make_uint2(lo2, hi2);
    }
  }
  __syncthreads();

  float cl = 0.f, wl = 0.f;
  if (h == 0) {
    float e2a[4] = {0.f, 0.f, 0.f, 0.f};
#pragma unroll
    for (int n = 0; n < 32; ++n) {
      uint2 v = *(const uint2*)&obuf[(n * 16 + c) * 68 + wg * 16 + g * 4];
      float s0 = eh[n][0] + bf2f((u16)(v.x & 0xffff));
      float s1 = eh[n][1] + bf2f((u16)(v.x >> 16));
      float s2 = eh[n][2] + bf2f((u16)(v.y & 0xffff));
      float s3 = eh[n][3] + bf2f((u16)(v.y >> 16));
      e2a[0] += s0 * s0; e2a[1] += s1 * s1;
      e2a[2] += s2 * s2; e2a[3] += s3 * s3;
    }
#pragma unroll
    for (int r = 0; r < 4; ++r) {
      e2a[r] += __shfl_xor(e2a[r], 1);
      e2a[r] += __shfl_xor(e2a[r], 2);
      e2a[r] += __shfl_xor(e2a[r], 4);
      e2a[r] += __shfl_xor(e2a[r], 8);
    }
    if (c == 0) {
#pragma unroll
      for (int r = 0; r < 4; ++r) {
        int row = wg * 16 + g * 4 + r;
        float l = Lb[row] + Lb[64 + row];
        float dot = Db[row] + Db[64 + row];
        float w = (l > 0.f) ? 1.f : 0.f;
        float cosv = (l > 0.f) ? dot / fmaxf(sqrtf(e2a[r]), 1e-8f * l) : 0.f;
        cl += w * (1.f - cosv);
        wl += w;
      }
    }
    cl += __shfl_xor(cl, 16); cl += __shfl_xor(cl, 32);
    wl += __shfl_xor(wl, 16); wl += __shfl_xor(wl, 32);
    if (lane == 0) { slb[wg] = cl; swb[wg] = wl; }
  }
  __syncthreads();
  if (threadIdx.x == 0) {
    pl[blockIdx.x] = slb[0] + slb[1] + slb[2] + slb[3];
    pw[blockIdx.x] = swb[0] + swb[1] + swb[2] + swb[3];
  }
}

// ---------------- k3: deterministic final reduction (256 partials) ----------------
__global__ void kreduce(const float* __restrict__ pl, const float* __restrict__ pw,
                        float* __restrict__ out) {
  __shared__ float sm[256], sw[256];
  int t = threadIdx.x;
  sm[t] = pl[t]; sw[t] = pw[t];
  __syncthreads();
#pragma unroll
  for (int st = 128; st >= 1; st >>= 1) {
    if (t < st) { sm[t] += sm[t + st]; sw[t] += sw[t + st]; }
    __syncthreads();
  }
  if (t == 0) {
    float cnt = sw[0];
    float loss = (cnt > 0.f) ? sm[0] / fmaxf(cnt, 1.f) : 0.f;
    out[0] = loss;
    out[1] = (cnt > 0.f) ? 1.f - loss : 0.f;
  }
}

extern "C" void kernel_launch(void* const* d_in, const int* in_sizes, int n_in,
                              void* d_out, int out_size, void* d_ws, size_t ws_size,
                              hipStream_t stream) {
  const float* pred = (const float*)d_in[0];
  const float* text = (const float*)d_in[1];
  const int* mask = (const int*)d_in[2];
  char* ws = (char*)d_ws;
  const size_t EB8 = (size_t)B_N * T_N * D_N;          // 8MB per fp8 tensor
  u8* EF = (u8*)ws;
  u8* ET = (u8*)(ws + EB8);
  float* pl = (float*)(ws + 2 * EB8);
  float* pw = (float*)(ws + 2 * EB8 + 4096);
  float* out = (float*)d_out;

  kprep<<<dim3(64, 8), dim3(256), 0, stream>>>(text, EF, ET);
  kflash<<<dim3(256), dim3(512), 0, stream>>>(pred, EF, ET, mask, pl, pw);
  kreduce<<<dim3(1), dim3(256), 0, stream>>>(pl, pw, out);
}